// Round 2
// baseline (96.817 us; speedup 1.0000x reference)
//
#include <hip/hip_runtime.h>

#define B_ 2048
#define S_ 512
#define T_ 17
#define NBF 683          // forward blocks (3 seqs each); bwd blocks follow
#define REC 40           // floats per sequence record in ws

#define UNPACK8(dst, q0, q1) do { dst[0]=(q0).x; dst[1]=(q0).y; dst[2]=(q0).z; dst[3]=(q0).w; \
                                  dst[4]=(q1).x; dst[5]=(q1).y; dst[6]=(q1).z; dst[7]=(q1).w; } while (0)

// broadcast: a_[i] = value of `srcf` on lane (group_base + i), via register bpermute
#define BCAST(dst, srcf) do {                                                     \
    int wi_ = __float_as_int(srcf);                                               \
    _Pragma("unroll")                                                             \
    for (int i_ = 0; i_ < T_; ++i_)                                               \
        dst[i_] = __int_as_float(__builtin_amdgcn_ds_bpermute(vbase + 4*i_, wi_));\
} while (0)

#define DOT17(a_) ( ((fmaf(a_[12],Ek[12],fmaf(a_[8],Ek[8],fmaf(a_[4],Ek[4],a_[0]*Ek[0])))   \
                   +  fmaf(a_[13],Ek[13],fmaf(a_[9],Ek[9],fmaf(a_[5],Ek[5],a_[1]*Ek[1]))))  \
                   + (fmaf(a_[14],Ek[14],fmaf(a_[10],Ek[10],fmaf(a_[6],Ek[6],a_[2]*Ek[2]))) \
                   +  fmaf(a_[15],Ek[15],fmaf(a_[11],Ek[11],fmaf(a_[7],Ek[7],a_[3]*Ek[3]))))) \
                   + a_[16]*Ek[16] )

#define MAX17(a_) fmaxf(fmaxf(fmaxf(fmaxf(fmaxf(a_[0],a_[1]),fmaxf(a_[2],a_[3])),  \
                      fmaxf(fmaxf(a_[4],a_[5]),fmaxf(a_[6],a_[7]))),               \
                      fmaxf(fmaxf(fmaxf(a_[8],a_[9]),fmaxf(a_[10],a_[11])),        \
                      fmaxf(fmaxf(a_[12],a_[13]),fmaxf(a_[14],a_[15])))), a_[16])

// forward step: w'_j = (sum_i w_i * E[i][j]) * d_j   (mask-gated, periodic renorm)
#define FSTEP(U, RN) do {                                       \
    float a_[T_]; BCAST(a_, w);                                 \
    float s_ = DOT17(a_);                                       \
    float r_ = 1.0f;                                            \
    if (RN) { float M_ = MAX17(a_); r_ = 1.0f/M_; Z += __logf(M_); } \
    float wn_ = s_ * dA[U];                                     \
    w = (mi[U] ? wn_ : w) * r_;                                 \
} while (0)

// backward step: v'_i = sum_j E[i][j] * (d_j * v_j)   (mask-gated, periodic renorm)
#define BSTEP(U, RN) do {                                       \
    float u_ = w * dA[U];                                       \
    float a_[T_]; BCAST(a_, u_);                                \
    float s_ = DOT17(a_);                                       \
    float r_ = 1.0f;                                            \
    if (RN) { float M_ = MAX17(a_); r_ = 1.0f/M_; Z += __logf(M_); } \
    w = (mi[U] ? s_ : w) * r_;                                  \
} while (0)

__global__ __launch_bounds__(64, 1) void crf_main(
    const float* __restrict__ inputs,   // [B,S,T]
    const int*   __restrict__ tags,     // [B,S]
    const int*   __restrict__ mask,     // [B,S]
    const float* __restrict__ trans,    // [T,T]
    const float* __restrict__ startt,   // [T]
    const float* __restrict__ endt,     // [T]
    float* __restrict__ ws)             // [B][REC]
{
    __shared__ float tlds[T_ * T_];

    const int lane = (int)threadIdx.x;
    int g = lane / T_; if (g > 3) g = 3;
    const int j = lane - g * T_;                 // state index 0..16
    const bool isF = ((int)blockIdx.x < NBF);
    const int blk = isF ? (int)blockIdx.x : ((int)blockIdx.x - NBF);
    const int braw = blk * 3 + g;
    const bool valid = (g < 3) && (braw < B_);
    const int b = valid ? braw : blk * 3;
    const int vbase = (g < 3 ? g : 2) * (T_ * 4);   // bpermute byte base of this group

    for (int k = lane; k < T_ * T_; k += 64) tlds[k] = trans[k];
    __syncthreads();

    // fwd lane j needs column j of E=exp(trans); bwd lane i needs row i
    float Ek[T_];
#pragma unroll
    for (int i = 0; i < T_; ++i)
        Ek[i] = __expf(isF ? tlds[i * T_ + j] : tlds[j * T_ + i]);

    const float* ip  = inputs + (size_t)b * (S_ * T_) + j;
    const int4* tp4 = (const int4*)(tags + (size_t)b * S_);
    const int4* mp4 = (const int4*)(mask + (size_t)b * S_);

    float w, Z = 0.0f, acc_emit = 0.0f, acc_tr = 0.0f, sbase = 0.0f;
    int msum = 0;

    float lgA[8], dA[8], lgB[8];
    int4 tb0, tb1, mb0, mb1;
    int tg[8], mi[8];

    if (isF) {
        // ---------------- FORWARD: t = 0..255 ----------------
#pragma unroll
        for (int u = 0; u < 8; ++u) lgA[u] = ip[u * T_];
        int4 ta0 = tp4[0], ta1 = tp4[1], ma0 = mp4[0], ma1 = mp4[1];
        UNPACK8(tg, ta0, ta1); UNPACK8(mi, ma0, ma1);
#pragma unroll
        for (int u = 0; u < 8; ++u) lgB[u] = ip[(8 + u) * T_];
        tb0 = tp4[2]; tb1 = tp4[3]; mb0 = mp4[2]; mb1 = mp4[3];
#pragma unroll
        for (int u = 0; u < 8; ++u) dA[u] = __expf(lgA[u]);

        const int tag0sav = tg[0];
        w = __expf(lgA[0] + startt[j]);
        int ptag = tg[0];
        acc_emit = (j == tg[0]) ? lgA[0] * (float)mi[0] : 0.0f;
        msum = mi[0];
#pragma unroll
        for (int u = 1; u < 8; ++u) {
            float mf = (float)mi[u];
            acc_emit = fmaf((j == tg[u]) ? mf : 0.0f, lgA[u], acc_emit);
            acc_tr   = fmaf(tlds[ptag * T_ + tg[u]], mf, acc_tr);
            ptag = tg[u]; msum += mi[u];
        }
        FSTEP(1,false); FSTEP(2,false); FSTEP(3,false);
        FSTEP(4,true);  FSTEP(5,false); FSTEP(6,false); FSTEP(7,false);

        for (int c = 1; c < 32; ++c) {
#pragma unroll
            for (int u = 0; u < 8; ++u) lgA[u] = lgB[u];
            int4 ca0 = tb0, ca1 = tb1, cm0 = mb0, cm1 = mb1;
            UNPACK8(tg, ca0, ca1); UNPACK8(mi, cm0, cm1);
            if (c < 31) {
#pragma unroll
                for (int u = 0; u < 8; ++u) lgB[u] = ip[(8 * (c + 1) + u) * T_];
                tb0 = tp4[2*(c+1)]; tb1 = tp4[2*(c+1)+1];
                mb0 = mp4[2*(c+1)]; mb1 = mp4[2*(c+1)+1];
            }
#pragma unroll
            for (int u = 0; u < 8; ++u) dA[u] = __expf(lgA[u]);
#pragma unroll
            for (int u = 0; u < 8; ++u) {
                float mf = (float)mi[u];
                acc_emit = fmaf((j == tg[u]) ? mf : 0.0f, lgA[u], acc_emit);
                acc_tr   = fmaf(tlds[ptag * T_ + tg[u]], mf, acc_tr);
                ptag = tg[u]; msum += mi[u];
            }
            FSTEP(0,true);  FSTEP(1,false); FSTEP(2,false); FSTEP(3,false);
            FSTEP(4,true);  FSTEP(5,false); FSTEP(6,false); FSTEP(7,false);
        }
        sbase = startt[tag0sav];
    } else {
        // ---------------- BACKWARD: t = 511..256 ----------------
        int ltag = 0; float lmf = 0.0f;
        int tbase = 504;
#pragma unroll
        for (int u = 0; u < 8; ++u) lgA[u] = ip[(504 + u) * T_];
        int4 ta0 = tp4[126], ta1 = tp4[127], ma0 = mp4[126], ma1 = mp4[127];
        UNPACK8(tg, ta0, ta1); UNPACK8(mi, ma0, ma1);
#pragma unroll
        for (int u = 0; u < 8; ++u) lgB[u] = ip[(496 + u) * T_];
        tb0 = tp4[124]; tb1 = tp4[125]; mb0 = mp4[124]; mb1 = mp4[125];
#pragma unroll
        for (int u = 0; u < 8; ++u) dA[u] = __expf(lgA[u]);

        w = __expf(endt[j]);            // v_{511}
        // span0 scores: emissions t=504..510 (exclude t=511), pairs t=505..511
#pragma unroll
        for (int u = 0; u < 8; ++u) {
            float mf = (float)mi[u];
            float gate = (u < 7) ? mf : 0.0f;
            acc_emit = fmaf((j == tg[u]) ? gate : 0.0f, lgA[u], acc_emit);
            msum += mi[u];
        }
#pragma unroll
        for (int u = 1; u < 8; ++u)
            acc_tr = fmaf(tlds[tg[u-1] * T_ + tg[u]], (float)mi[u], acc_tr);
        ltag = tg[0]; lmf = (float)mi[0];

        BSTEP(7,true);  BSTEP(6,false); BSTEP(5,false); BSTEP(4,false);
        BSTEP(3,true);  BSTEP(2,false); BSTEP(1,false); BSTEP(0,false);

        for (int c = 1; c < 32; ++c) {
            tbase = 504 - 8 * c;
#pragma unroll
            for (int u = 0; u < 8; ++u) lgA[u] = lgB[u];
            int4 ca0 = tb0, ca1 = tb1, cm0 = mb0, cm1 = mb1;
            UNPACK8(tg, ca0, ca1); UNPACK8(mi, cm0, cm1);
            if (c < 31) {
                int nb = (tbase - 8) >> 2;   // int4 index of next (lower) span
#pragma unroll
                for (int u = 0; u < 8; ++u) lgB[u] = ip[(tbase - 8 + u) * T_];
                tb0 = tp4[nb]; tb1 = tp4[nb + 1];
                mb0 = mp4[nb]; mb1 = mp4[nb + 1];
            }
#pragma unroll
            for (int u = 0; u < 8; ++u) dA[u] = __expf(lgA[u]);
#pragma unroll
            for (int u = 0; u < 8; ++u) {
                float mf = (float)mi[u];
                acc_emit = fmaf((j == tg[u]) ? mf : 0.0f, lgA[u], acc_emit);
                msum += mi[u];
            }
#pragma unroll
            for (int u = 1; u < 8; ++u)
                acc_tr = fmaf(tlds[tg[u-1] * T_ + tg[u]], (float)mi[u], acc_tr);
            acc_tr = fmaf(tlds[tg[7] * T_ + ltag], lmf, acc_tr);   // cross pair t=tbase+8
            ltag = tg[0]; lmf = (float)mi[0];

            BSTEP(7,true);  BSTEP(6,false); BSTEP(5,false); BSTEP(4,false);
            BSTEP(3,true);  BSTEP(2,false); BSTEP(1,false); BSTEP(0,false);
        }
        // final pair t=256: (tag_255 -> tag_256), mask m_256
        int t255 = tags[(size_t)b * S_ + 255];
        acc_tr = fmaf(tlds[t255 * T_ + ltag], lmf, acc_tr);
        sbase = 0.0f;
    }

    // ---- per-group reduction of acc_emit (register bpermute, no LDS) ----
    float e_[T_]; BCAST(e_, acc_emit);
    float esum = ((((e_[0]+e_[1])+(e_[2]+e_[3]))+((e_[4]+e_[5])+(e_[6]+e_[7])))
               + (((e_[8]+e_[9])+(e_[10]+e_[11]))+((e_[12]+e_[13])+(e_[14]+e_[15])))) + e_[16];

    float* rec = ws + (size_t)b * REC + (isF ? 0 : 20);
    if (valid) {
        rec[j] = w;                                  // wf (fwd) or v (bwd), 17 lanes
        if (j == 0) {
            rec[17] = Z;
            rec[18] = sbase + acc_tr + esum;
            rec[19] = (float)msum;
        }
    }
}

__global__ __launch_bounds__(256) void crf_combine(
    const float* __restrict__ inputs, const int* __restrict__ tags,
    const int* __restrict__ mask, const float* __restrict__ endt,
    float* __restrict__ ws)
{
    int s = (int)blockIdx.x * 256 + (int)threadIdx.x;
    if (s >= B_) return;
    float* rec = ws + (size_t)s * REC;
    float dot = 0.0f;
#pragma unroll
    for (int i = 0; i < T_; ++i) dot = fmaf(rec[i], rec[20 + i], dot);
    float denom = rec[17] + rec[37] + __logf(dot);
    int msum = (int)(rec[19] + rec[39] + 0.5f);
    int last_idx = msum - 1; if (last_idx < 0) last_idx = 0;
    int last_tag = tags[(size_t)s * S_ + last_idx];
    float mlast = (float)mask[(size_t)s * S_ + (S_ - 1)];
    float last_in = inputs[((size_t)s * S_ + (S_ - 1)) * T_ + last_tag];
    float score = rec[18] + rec[38] + endt[last_tag] + last_in * mlast;
    rec[19] = score - denom;     // per-seq result (own record slot, race-free)
}

__global__ __launch_bounds__(256) void reduce_sum(const float* __restrict__ ws,
                                                  float* __restrict__ out)
{
    __shared__ float sm[256];
    float s = 0.0f;
    for (int i = (int)threadIdx.x; i < B_; i += 256) s += ws[(size_t)i * REC + 19];
    sm[threadIdx.x] = s;
    __syncthreads();
    for (int k = 128; k >= 1; k >>= 1) {
        if ((int)threadIdx.x < k) sm[threadIdx.x] += sm[threadIdx.x + k];
        __syncthreads();
    }
    if (threadIdx.x == 0) out[0] = sm[0];
}

extern "C" void kernel_launch(void* const* d_in, const int* in_sizes, int n_in,
                              void* d_out, int out_size, void* d_ws, size_t ws_size,
                              hipStream_t stream)
{
    const float* inputs = (const float*)d_in[0];
    const int*   tags   = (const int*)d_in[1];
    const int*   mask   = (const int*)d_in[2];
    const float* trans  = (const float*)d_in[3];
    const float* startt = (const float*)d_in[4];
    const float* endt   = (const float*)d_in[5];
    float* out = (float*)d_out;
    float* ws  = (float*)d_ws;

    crf_main<<<2 * NBF, 64, 0, stream>>>(inputs, tags, mask, trans, startt, endt, ws);
    crf_combine<<<(B_ + 255) / 256, 256, 0, stream>>>(inputs, tags, mask, endt, ws);
    reduce_sum<<<1, 256, 0, stream>>>(ws, out);
}